// Round 1
// baseline (128.871 us; speedup 1.0000x reference)
//
#include <hip/hip_runtime.h>

#define B_   16
#define C_   256
#define HW_  4096
#define DQK  131072     // 32*4096, q/k feature dim per batch
#define DV   1048576    // 256*4096, v feature dim per batch

using bf16x8  = __attribute__((ext_vector_type(8))) __bf16;
using ushort8 = __attribute__((ext_vector_type(8))) unsigned short;
using u16x4   = __attribute__((ext_vector_type(4))) unsigned short;
using f32x4   = __attribute__((ext_vector_type(4))) float;

static __device__ __forceinline__ unsigned short f2bf(float f) {
    union { float f; unsigned u; } v; v.f = f;
    unsigned r = v.u + 0x7FFFu + ((v.u >> 16) & 1u);
    return (unsigned short)(r >> 16);
}
static __device__ __forceinline__ float bf2f(unsigned short h) {
    union { unsigned u; float f; } v; v.u = ((unsigned)h) << 16;
    return v.f;
}

// ---------------- pack weights: Wh/Wl = hi/lo split of [wq;wk] (64x256), Wv bf16 (256x256)
__global__ __launch_bounds__(256) void k_pack(const float* wq, const float* wk, const float* wv,
                                              unsigned short* Wh, unsigned short* Wl, unsigned short* Wv) {
    int idx = blockIdx.x * 256 + threadIdx.x;   // 81920 total
    if (idx < 16384) {
        float f = (idx < 8192) ? wq[idx] : wk[idx - 8192];
        unsigned short hi = f2bf(f);
        Wh[idx] = hi;
        Wl[idx] = f2bf(f - bf2f(hi));
    } else {
        int i = idx - 16384;
        Wv[i] = f2bf(wv[i]);
    }
}

// ---------------- transpose+convert: x fp32 [b][c][p] -> Xt bf16 [b][p][c]
__global__ __launch_bounds__(256) void k_transpose(const float* x, unsigned short* Xt) {
    __shared__ unsigned short T[64][68];
    int b = blockIdx.z, c0 = blockIdx.y * 64, p0 = blockIdx.x * 64;
    int t = threadIdx.x;
    const float* xb = x + (size_t)b * DV;
    for (int j = 0; j < 4; j++) {
        int c  = (t >> 4) + j * 16;
        int pq = t & 15;
        f32x4 v = *(const f32x4*)(xb + (size_t)(c0 + c) * HW_ + p0 + pq * 4);
        T[pq*4+0][c] = f2bf(v[0]);
        T[pq*4+1][c] = f2bf(v[1]);
        T[pq*4+2][c] = f2bf(v[2]);
        T[pq*4+3][c] = f2bf(v[3]);
    }
    __syncthreads();
    unsigned short* xtb = Xt + (size_t)b * DV;
    for (int j = 0; j < 4; j++) {
        int p  = (t >> 4) + j * 16;
        int cq = t & 15;
        u16x4 u = *(const u16x4*)&T[p][cq * 4];
        *(u16x4*)(xtb + (size_t)(p0 + p) * C_ + c0 + cq * 4) = u;
    }
}

// ---------------- v GEMM: vout[b][m][n] = sum_k Wv[m][k] * Xt[b][n][k] + bv[m]
// tile BM=64 BN=128 BK=32, 4 waves (2x2), wave tile 32x64, mfma 16x16x32 bf16
__global__ __launch_bounds__(256) void k_gemm_v(const unsigned short* __restrict__ Wv,
                                                const unsigned short* __restrict__ Xt,
                                                const float* __restrict__ bv, float* __restrict__ vout) {
    __shared__ __align__(16) unsigned short As[64][40];
    __shared__ __align__(16) unsigned short Bs[128][40];
    int b  = blockIdx.z;
    int m0 = blockIdx.y * 64;
    int n0 = blockIdx.x * 128;
    int t = threadIdx.x;
    int lane = t & 63, wid = t >> 6;
    int wm = wid >> 1, wn = wid & 1;
    int lr = lane & 15, kg = lane >> 4;

    const unsigned short* xtb = Xt + (size_t)b * DV;
    int am = t >> 2, akq = (t & 3) * 8;
    int bn = t >> 1, bkh = (t & 1) * 16;

    f32x4 acc[2][4];
    for (int mi = 0; mi < 2; mi++)
        for (int ni = 0; ni < 4; ni++) acc[mi][ni] = (f32x4){0.f, 0.f, 0.f, 0.f};

    for (int kk = 0; kk < 8; kk++) {
        int k0 = kk * 32;
        *(ushort8*)&As[am][akq] = *(const ushort8*)(Wv + (size_t)(m0 + am) * 256 + k0 + akq);
        const unsigned short* src = xtb + (size_t)(n0 + bn) * C_ + k0 + bkh;
        *(ushort8*)&Bs[bn][bkh]     = *(const ushort8*)(src);
        *(ushort8*)&Bs[bn][bkh + 8] = *(const ushort8*)(src + 8);
        __syncthreads();
        bf16x8 a[2], bb[4];
        for (int mi = 0; mi < 2; mi++) a[mi]  = *(const bf16x8*)&As[wm * 32 + mi * 16 + lr][kg * 8];
        for (int ni = 0; ni < 4; ni++) bb[ni] = *(const bf16x8*)&Bs[wn * 64 + ni * 16 + lr][kg * 8];
        for (int mi = 0; mi < 2; mi++)
            for (int ni = 0; ni < 4; ni++)
                acc[mi][ni] = __builtin_amdgcn_mfma_f32_16x16x32_bf16(a[mi], bb[ni], acc[mi][ni], 0, 0, 0);
        __syncthreads();
    }
    for (int mi = 0; mi < 2; mi++) {
        int mbase = m0 + wm * 32 + mi * 16 + kg * 4;
        for (int i = 0; i < 4; i++) {
            float bias = bv[mbase + i];
            for (int ni = 0; ni < 4; ni++) {
                int n = n0 + wn * 64 + ni * 16 + lr;
                vout[(size_t)b * DV + (size_t)(mbase + i) * HW_ + n] = acc[mi][ni][i] + bias;
            }
        }
    }
}

// ---------------- qk GEMM, split-bf16 precision: rows 0..31 q, 32..63 k; fp32 out
__global__ __launch_bounds__(256) void k_gemm_qk(const unsigned short* __restrict__ Wh,
                                                 const unsigned short* __restrict__ Wl,
                                                 const float* __restrict__ x,
                                                 const float* __restrict__ bq, const float* __restrict__ bk,
                                                 float* __restrict__ QF, float* __restrict__ KF) {
    __shared__ __align__(16) unsigned short Ah[64][40], Al[64][40];
    __shared__ __align__(16) unsigned short Bh[128][40], Bl[128][40];
    int b  = blockIdx.y;
    int n0 = blockIdx.x * 128;
    int t = threadIdx.x;
    int lane = t & 63, wid = t >> 6;
    int wm = wid >> 1, wn = wid & 1;
    int lr = lane & 15, kg = lane >> 4;

    const float* xb = x + (size_t)b * DV;
    int am = t >> 2, akq = (t & 3) * 8;
    int bkr = t >> 3, bnq = (t & 7) * 16;

    f32x4 acc[2][4];
    for (int mi = 0; mi < 2; mi++)
        for (int ni = 0; ni < 4; ni++) acc[mi][ni] = (f32x4){0.f, 0.f, 0.f, 0.f};

    for (int kk = 0; kk < 8; kk++) {
        int k0 = kk * 32;
        *(ushort8*)&Ah[am][akq] = *(const ushort8*)(Wh + (size_t)am * 256 + k0 + akq);
        *(ushort8*)&Al[am][akq] = *(const ushort8*)(Wl + (size_t)am * 256 + k0 + akq);
        const float* srcb = xb + (size_t)(k0 + bkr) * HW_ + n0 + bnq;
        for (int e4 = 0; e4 < 4; e4++) {
            f32x4 v = *(const f32x4*)(srcb + e4 * 4);
            for (int e = 0; e < 4; e++) {
                float f = v[e];
                unsigned short hi = f2bf(f);
                Bh[bnq + e4 * 4 + e][bkr] = hi;
                Bl[bnq + e4 * 4 + e][bkr] = f2bf(f - bf2f(hi));
            }
        }
        __syncthreads();
        bf16x8 ah[2], al[2], bh[4], bl[4];
        for (int mi = 0; mi < 2; mi++) {
            ah[mi] = *(const bf16x8*)&Ah[wm * 32 + mi * 16 + lr][kg * 8];
            al[mi] = *(const bf16x8*)&Al[wm * 32 + mi * 16 + lr][kg * 8];
        }
        for (int ni = 0; ni < 4; ni++) {
            bh[ni] = *(const bf16x8*)&Bh[wn * 64 + ni * 16 + lr][kg * 8];
            bl[ni] = *(const bf16x8*)&Bl[wn * 64 + ni * 16 + lr][kg * 8];
        }
        for (int mi = 0; mi < 2; mi++)
            for (int ni = 0; ni < 4; ni++) {
                acc[mi][ni] = __builtin_amdgcn_mfma_f32_16x16x32_bf16(ah[mi], bh[ni], acc[mi][ni], 0, 0, 0);
                acc[mi][ni] = __builtin_amdgcn_mfma_f32_16x16x32_bf16(ah[mi], bl[ni], acc[mi][ni], 0, 0, 0);
                acc[mi][ni] = __builtin_amdgcn_mfma_f32_16x16x32_bf16(al[mi], bh[ni], acc[mi][ni], 0, 0, 0);
            }
        __syncthreads();
    }
    for (int mi = 0; mi < 2; mi++) {
        int mbase = wm * 32 + mi * 16 + kg * 4;
        for (int i = 0; i < 4; i++) {
            int m = mbase + i;
            float bias = (m < 32) ? bq[m] : bk[m - 32];
            for (int ni = 0; ni < 4; ni++) {
                int n = n0 + wn * 64 + ni * 16 + lr;
                float val = acc[mi][ni][i] + bias;
                if (m < 32) QF[(size_t)b * DQK + (size_t)m * HW_ + n] = val;
                else        KF[(size_t)b * DQK + (size_t)(m - 32) * HW_ + n] = val;
            }
        }
    }
}

// ---------------- scores: S[p] for 128 (b, partner) pairs; deterministic block reduction
__global__ __launch_bounds__(256) void k_scores(const float* __restrict__ QF, const float* __restrict__ KF,
                                                float* __restrict__ S) {
    int p = blockIdx.x;              // 0..127 : p = b*8 + j
    int b = p >> 3, j = p & 7;
    int h = b >> 2, w = b & 3;
    int bp = (j < 4) ? (j * 4 + w) : (h * 4 + (j - 4));
    int t = threadIdx.x;
    const f32x4* Q4 = (const f32x4*)(QF + (size_t)b * DQK);
    const f32x4* K4 = (const f32x4*)(KF + (size_t)bp * DQK);
    float s = 0.f;
    for (int it = 0; it < 128; it++) {
        int i4 = it * 256 + t;
        f32x4 q = Q4[i4], k = K4[i4];
        s += q[0] * k[0] + q[1] * k[1] + q[2] * k[2] + q[3] * k[3];
    }
    for (int off = 32; off > 0; off >>= 1) s += __shfl_down(s, off);
    __shared__ float ws4[4];
    if ((t & 63) == 0) ws4[t >> 6] = s;
    __syncthreads();
    if (t == 0) S[p] = ws4[0] + ws4[1] + ws4[2] + ws4[3];
}

// ---------------- softmax over 8 + fold gamma -> 16x16 mixing matrix M
__global__ void k_softmax(const float* __restrict__ S, const float* __restrict__ gamma,
                          float* __restrict__ Mm) {
    int t = threadIdx.x;
    if (t < 16) {
        int b = t, h = b >> 2, w = b & 3;
        float e[8];
        for (int j = 0; j < 8; j++) e[j] = S[b * 8 + j];
        e[h] = -INFINITY;                      // masked diagonal of eH
        float m = e[0];
        for (int j = 1; j < 8; j++) m = fmaxf(m, e[j]);
        float a[8], sum = 0.f;
        for (int j = 0; j < 8; j++) { a[j] = expf(e[j] - m); sum += a[j]; }
        float inv = 1.0f / sum;
        float g = gamma[0];
        float row[16];
        for (int c = 0; c < 16; c++) row[c] = 0.f;
        for (int gg = 0; gg < 4; gg++) if (gg != h) row[gg * 4 + w] += a[gg] * inv;       // eH partners
        for (int gg = 0; gg < 4; gg++) row[h * 4 + gg] += a[4 + gg] * inv;                // eW partners
        for (int c = 0; c < 16; c++) Mm[b * 16 + c] = row[c] * g;
    }
}

// ---------------- final mix: out[b][i] = sum_bp M[b][bp]*v[bp][i] + x[b][i]  (in-place in d_out, thread-local)
__global__ __launch_bounds__(256) void k_out(const float* __restrict__ Mm, const float* __restrict__ x,
                                             float* vo) {
    __shared__ float Ms[256];
    int t = threadIdx.x;
    Ms[t] = Mm[t];
    __syncthreads();
    size_t i0 = ((size_t)blockIdx.x * 256 + t) * 4;
    f32x4 acc[16];
    for (int b = 0; b < 16; b++) acc[b] = *(const f32x4*)(x + (size_t)b * DV + i0);
    for (int bp = 0; bp < 16; bp++) {
        f32x4 v = *(const f32x4*)(vo + (size_t)bp * DV + i0);
        for (int b = 0; b < 16; b++) {
            float wgt = Ms[b * 16 + bp];
            acc[b] += wgt * v;
        }
    }
    for (int b = 0; b < 16; b++) *(f32x4*)(vo + (size_t)b * DV + i0) = acc[b];
}

extern "C" void kernel_launch(void* const* d_in, const int* in_sizes, int n_in,
                              void* d_out, int out_size, void* d_ws, size_t ws_size,
                              hipStream_t stream) {
    (void)in_sizes; (void)n_in; (void)out_size; (void)ws_size;
    const float* x     = (const float*)d_in[0];
    const float* wq    = (const float*)d_in[1];
    const float* bq    = (const float*)d_in[2];
    const float* wk    = (const float*)d_in[3];
    const float* bk    = (const float*)d_in[4];
    const float* wv    = (const float*)d_in[5];
    const float* bv    = (const float*)d_in[6];
    const float* gamma = (const float*)d_in[7];

    char* ws = (char*)d_ws;
    // ws layout (bytes): Wh 32768 | Wl 32768 | Wv 131072 | QF 8388608 | KF 8388608 | S 512 | M 1024 | Xt 33554432
    unsigned short* Wh = (unsigned short*)(ws + 0);
    unsigned short* Wl = (unsigned short*)(ws + 32768);
    unsigned short* Wv = (unsigned short*)(ws + 65536);
    float*          QF = (float*)(ws + 196608);
    float*          KF = (float*)(ws + 8585216);
    float*          S  = (float*)(ws + 16973824);
    float*          Mm = (float*)(ws + 16974336);
    unsigned short* Xt = (unsigned short*)(ws + 16975360);   // total 50,529,792 bytes
    float*          vo = (float*)d_out;

    k_pack     <<<320, 256, 0, stream>>>(wq, wk, wv, Wh, Wl, Wv);
    k_transpose<<<dim3(64, 4, 16), 256, 0, stream>>>(x, Xt);
    k_gemm_qk  <<<dim3(32, 16),    256, 0, stream>>>(Wh, Wl, x, bq, bk, QF, KF);
    k_gemm_v   <<<dim3(32, 4, 16), 256, 0, stream>>>(Wv, Xt, bv, vo);
    k_scores   <<<128, 256, 0, stream>>>(QF, KF, S);
    k_softmax  <<<1, 64, 0, stream>>>(S, gamma, Mm);
    k_out      <<<1024, 256, 0, stream>>>(Mm, x, vo);
}

// Round 2
// 94.888 us; speedup vs baseline: 1.3581x; 1.3581x over previous
//
#include <hip/hip_runtime.h>

#define B_   16
#define C_   256
#define HW_  4096
#define DQK  131072     // 32*4096, q/k feature dim per batch
#define DV   1048576    // 256*4096, v feature dim per batch

using bf16x8  = __attribute__((ext_vector_type(8))) __bf16;
using ushort8 = __attribute__((ext_vector_type(8))) unsigned short;
using u16x4   = __attribute__((ext_vector_type(4))) unsigned short;
using f32x4   = __attribute__((ext_vector_type(4))) float;

static __device__ __forceinline__ unsigned short f2bf(float f) {
    union { float f; unsigned u; } v; v.f = f;
    unsigned r = v.u + 0x7FFFu + ((v.u >> 16) & 1u);
    return (unsigned short)(r >> 16);
}
static __device__ __forceinline__ float bf2f(unsigned short h) {
    union { unsigned u; float f; } v; v.u = ((unsigned)h) << 16;
    return v.f;
}

// ---------------- pack weights: Wh/Wl = hi/lo split of [wq;wk] (64x256), Wv bf16 (256x256)
__global__ __launch_bounds__(256) void k_pack(const float* wq, const float* wk, const float* wv,
                                              unsigned short* Wh, unsigned short* Wl, unsigned short* Wv) {
    int idx = blockIdx.x * 256 + threadIdx.x;   // 81920 total
    if (idx < 16384) {
        float f = (idx < 8192) ? wq[idx] : wk[idx - 8192];
        unsigned short hi = f2bf(f);
        Wh[idx] = hi;
        Wl[idx] = f2bf(f - bf2f(hi));
    } else {
        int i = idx - 16384;
        Wv[i] = f2bf(wv[i]);
    }
}

// ---------------- qk GEMM, split-bf16 precision: rows 0..31 q, 32..63 k; fp32 out
__global__ __launch_bounds__(256) void k_gemm_qk(const unsigned short* __restrict__ Wh,
                                                 const unsigned short* __restrict__ Wl,
                                                 const float* __restrict__ x,
                                                 const float* __restrict__ bq, const float* __restrict__ bk,
                                                 float* __restrict__ QF, float* __restrict__ KF) {
    __shared__ __align__(16) unsigned short Ah[64][40], Al[64][40];
    __shared__ __align__(16) unsigned short Bh[128][40], Bl[128][40];
    int b  = blockIdx.y;
    int n0 = blockIdx.x * 128;
    int t = threadIdx.x;
    int lane = t & 63, wid = t >> 6;
    int wm = wid >> 1, wn = wid & 1;
    int lr = lane & 15, kg = lane >> 4;

    const float* xb = x + (size_t)b * DV;
    int am = t >> 2, akq = (t & 3) * 8;
    int bkr = t >> 3, bnq = (t & 7) * 16;

    f32x4 acc[2][4];
    for (int mi = 0; mi < 2; mi++)
        for (int ni = 0; ni < 4; ni++) acc[mi][ni] = (f32x4){0.f, 0.f, 0.f, 0.f};

    for (int kk = 0; kk < 8; kk++) {
        int k0 = kk * 32;
        *(ushort8*)&Ah[am][akq] = *(const ushort8*)(Wh + (size_t)am * 256 + k0 + akq);
        *(ushort8*)&Al[am][akq] = *(const ushort8*)(Wl + (size_t)am * 256 + k0 + akq);
        const float* srcb = xb + (size_t)(k0 + bkr) * HW_ + n0 + bnq;
        for (int e4 = 0; e4 < 4; e4++) {
            f32x4 v = *(const f32x4*)(srcb + e4 * 4);
            for (int e = 0; e < 4; e++) {
                float f = v[e];
                unsigned short hi = f2bf(f);
                Bh[bnq + e4 * 4 + e][bkr] = hi;
                Bl[bnq + e4 * 4 + e][bkr] = f2bf(f - bf2f(hi));
            }
        }
        __syncthreads();
        bf16x8 ah[2], al[2], bh[4], bl[4];
        for (int mi = 0; mi < 2; mi++) {
            ah[mi] = *(const bf16x8*)&Ah[wm * 32 + mi * 16 + lr][kg * 8];
            al[mi] = *(const bf16x8*)&Al[wm * 32 + mi * 16 + lr][kg * 8];
        }
        for (int ni = 0; ni < 4; ni++) {
            bh[ni] = *(const bf16x8*)&Bh[wn * 64 + ni * 16 + lr][kg * 8];
            bl[ni] = *(const bf16x8*)&Bl[wn * 64 + ni * 16 + lr][kg * 8];
        }
        for (int mi = 0; mi < 2; mi++)
            for (int ni = 0; ni < 4; ni++) {
                acc[mi][ni] = __builtin_amdgcn_mfma_f32_16x16x32_bf16(ah[mi], bh[ni], acc[mi][ni], 0, 0, 0);
                acc[mi][ni] = __builtin_amdgcn_mfma_f32_16x16x32_bf16(ah[mi], bl[ni], acc[mi][ni], 0, 0, 0);
                acc[mi][ni] = __builtin_amdgcn_mfma_f32_16x16x32_bf16(al[mi], bh[ni], acc[mi][ni], 0, 0, 0);
            }
        __syncthreads();
    }
    for (int mi = 0; mi < 2; mi++) {
        int mbase = wm * 32 + mi * 16 + kg * 4;
        for (int i = 0; i < 4; i++) {
            int m = mbase + i;
            float bias = (m < 32) ? bq[m] : bk[m - 32];
            for (int ni = 0; ni < 4; ni++) {
                int n = n0 + wn * 64 + ni * 16 + lr;
                float val = acc[mi][ni][i] + bias;
                if (m < 32) QF[(size_t)b * DQK + (size_t)m * HW_ + n] = val;
                else        KF[(size_t)b * DQK + (size_t)(m - 32) * HW_ + n] = val;
            }
        }
    }
}

// ---------------- scores partials: 128 pairs x 8 slices, deterministic
__global__ __launch_bounds__(256) void k_scores_part(const float* __restrict__ QF, const float* __restrict__ KF,
                                                     float* __restrict__ Sp) {
    int bx = blockIdx.x;             // 0..1023
    int p = bx >> 3, sl = bx & 7;
    int b = p >> 3, j = p & 7;
    int h = b >> 2, w = b & 3;
    int bp = (j < 4) ? (j * 4 + w) : (h * 4 + (j - 4));
    int t = threadIdx.x;
    const f32x4* Q4 = (const f32x4*)(QF + (size_t)b * DQK);
    const f32x4* K4 = (const f32x4*)(KF + (size_t)bp * DQK);
    float s = 0.f;
    for (int it = 0; it < 16; it++) {
        int i4 = sl * 4096 + it * 256 + t;
        f32x4 q = Q4[i4], k = K4[i4];
        s += q[0] * k[0] + q[1] * k[1] + q[2] * k[2] + q[3] * k[3];
    }
    for (int off = 32; off > 0; off >>= 1) s += __shfl_down(s, off);
    __shared__ float ws4[4];
    if ((t & 63) == 0) ws4[t >> 6] = s;
    __syncthreads();
    if (t == 0) Sp[bx] = ws4[0] + ws4[1] + ws4[2] + ws4[3];
}

// ---------------- softmax over 8 + fold gamma -> 16x16 mixing matrix M [0..255] + rowsum [256..271]
__global__ void k_softmax(const float* __restrict__ Sp, const float* __restrict__ gamma,
                          float* __restrict__ Mm) {
    int t = threadIdx.x;
    if (t < 16) {
        int b = t, h = b >> 2, w = b & 3;
        float e[8];
        for (int j = 0; j < 8; j++) {
            float s = 0.f;
            for (int sl = 0; sl < 8; sl++) s += Sp[(b * 8 + j) * 8 + sl];
            e[j] = s;
        }
        e[h] = -INFINITY;                      // masked diagonal of eH
        float m = e[0];
        for (int j = 1; j < 8; j++) m = fmaxf(m, e[j]);
        float a[8], sum = 0.f;
        for (int j = 0; j < 8; j++) { a[j] = expf(e[j] - m); sum += a[j]; }
        float inv = 1.0f / sum;
        float g = gamma[0];
        float row[16];
        for (int c = 0; c < 16; c++) row[c] = 0.f;
        for (int gg = 0; gg < 4; gg++) if (gg != h) row[gg * 4 + w] += a[gg] * inv;       // eH partners
        for (int gg = 0; gg < 4; gg++) row[h * 4 + gg] += a[4 + gg] * inv;                // eW partners
        for (int c = 0; c < 16; c++) Mm[b * 16 + c] = row[c] * g;
        Mm[256 + b] = g;                       // rowsum of M (softmax rows sum to 1)
    }
}

// ---------------- mix + transpose + convert: Xm[b][p][c] bf16 = sum_bp M[b][bp] * x[bp][c][p]
// tile: 32 c x 32 p per block, all 16 batches in/out
__global__ __launch_bounds__(256) void k_mix(const float* __restrict__ Mm, const float* __restrict__ x,
                                             unsigned short* __restrict__ Xm) {
    __shared__ float Ms[256];
    __shared__ unsigned short T[16][32][36];
    int t = threadIdx.x;
    int p0 = blockIdx.x * 32, c0 = blockIdx.y * 32;
    Ms[t] = Mm[t];

    int c_l = t >> 3, p4 = t & 7;          // phase A: thread owns (c_l, p = p4*4..p4*4+3)
    f32x4 in4[16];
    for (int bp = 0; bp < 16; bp++)
        in4[bp] = *(const f32x4*)(x + (size_t)bp * DV + (size_t)(c0 + c_l) * HW_ + p0 + p4 * 4);
    __syncthreads();
    for (int b = 0; b < 16; b++) {
        f32x4 acc = (f32x4){0.f, 0.f, 0.f, 0.f};
        for (int bp = 0; bp < 16; bp++) {
            float wgt = Ms[b * 16 + bp];
            acc += wgt * in4[bp];
        }
        for (int e = 0; e < 4; e++) T[b][p4 * 4 + e][c_l] = f2bf(acc[e]);
    }
    __syncthreads();
    int p_l = t >> 3, cq = t & 7;          // phase B: transposed readout
    for (int b = 0; b < 16; b++) {
        u16x4 v = *(const u16x4*)&T[b][p_l][cq * 4];
        *(u16x4*)(Xm + (size_t)b * DV + (size_t)(p0 + p_l) * C_ + c0 + cq * 4) = v;
    }
}

// ---------------- v GEMM + bias + residual: out[b][m][n] = sum_k Wv[m][k]*Xm[b][n][k] + rs[b]*bv[m] + x[b][m][n]
__global__ __launch_bounds__(256) void k_gemm_v_res(const unsigned short* __restrict__ Wv,
                                                    const unsigned short* __restrict__ Xm,
                                                    const float* __restrict__ bv,
                                                    const float* __restrict__ MmRs,
                                                    const float* __restrict__ x,
                                                    float* __restrict__ out) {
    __shared__ __align__(16) unsigned short As[64][40];
    __shared__ __align__(16) unsigned short Bs[128][40];
    int b  = blockIdx.z;
    int m0 = blockIdx.y * 64;
    int n0 = blockIdx.x * 128;
    int t = threadIdx.x;
    int lane = t & 63, wid = t >> 6;
    int wm = wid >> 1, wn = wid & 1;
    int lr = lane & 15, kg = lane >> 4;

    const unsigned short* xtb = Xm + (size_t)b * DV;
    int am = t >> 2, akq = (t & 3) * 8;
    int bn = t >> 1, bkh = (t & 1) * 16;

    f32x4 acc[2][4];
    for (int mi = 0; mi < 2; mi++)
        for (int ni = 0; ni < 4; ni++) acc[mi][ni] = (f32x4){0.f, 0.f, 0.f, 0.f};

    for (int kk = 0; kk < 8; kk++) {
        int k0 = kk * 32;
        *(ushort8*)&As[am][akq] = *(const ushort8*)(Wv + (size_t)(m0 + am) * 256 + k0 + akq);
        const unsigned short* src = xtb + (size_t)(n0 + bn) * C_ + k0 + bkh;
        *(ushort8*)&Bs[bn][bkh]     = *(const ushort8*)(src);
        *(ushort8*)&Bs[bn][bkh + 8] = *(const ushort8*)(src + 8);
        __syncthreads();
        bf16x8 a[2], bb[4];
        for (int mi = 0; mi < 2; mi++) a[mi]  = *(const bf16x8*)&As[wm * 32 + mi * 16 + lr][kg * 8];
        for (int ni = 0; ni < 4; ni++) bb[ni] = *(const bf16x8*)&Bs[wn * 64 + ni * 16 + lr][kg * 8];
        for (int mi = 0; mi < 2; mi++)
            for (int ni = 0; ni < 4; ni++)
                acc[mi][ni] = __builtin_amdgcn_mfma_f32_16x16x32_bf16(a[mi], bb[ni], acc[mi][ni], 0, 0, 0);
        __syncthreads();
    }
    float rs_b = MmRs[256 + b];
    for (int mi = 0; mi < 2; mi++) {
        int mbase = m0 + wm * 32 + mi * 16 + kg * 4;
        for (int i = 0; i < 4; i++) {
            int m = mbase + i;
            float bias = rs_b * bv[m];
            for (int ni = 0; ni < 4; ni++) {
                int n = n0 + wn * 64 + ni * 16 + lr;
                size_t idx = (size_t)b * DV + (size_t)m * HW_ + n;
                out[idx] = acc[mi][ni][i] + bias + x[idx];
            }
        }
    }
}

extern "C" void kernel_launch(void* const* d_in, const int* in_sizes, int n_in,
                              void* d_out, int out_size, void* d_ws, size_t ws_size,
                              hipStream_t stream) {
    (void)in_sizes; (void)n_in; (void)out_size; (void)ws_size;
    const float* x     = (const float*)d_in[0];
    const float* wq    = (const float*)d_in[1];
    const float* bq    = (const float*)d_in[2];
    const float* wk    = (const float*)d_in[3];
    const float* bk    = (const float*)d_in[4];
    const float* wv    = (const float*)d_in[5];
    const float* bv    = (const float*)d_in[6];
    const float* gamma = (const float*)d_in[7];

    char* ws = (char*)d_ws;
    // ws layout (bytes): Wh 32768 | Wl 32768 | Wv 131072 | QF 8388608 | KF 8388608 | Xm 33554432
    // Sp (4096) and Mm (1088) alias the Wh region — Wh/Wl are dead after k_gemm_qk.
    unsigned short* Wh = (unsigned short*)(ws + 0);
    unsigned short* Wl = (unsigned short*)(ws + 32768);
    unsigned short* Wv = (unsigned short*)(ws + 65536);
    float*          QF = (float*)(ws + 196608);
    float*          KF = (float*)(ws + 8585216);
    unsigned short* Xm = (unsigned short*)(ws + 16973824);   // + 33554432 = 50528256 total
    float*          Sp = (float*)(ws + 0);                   // aliases Wh (dead by then)
    float*          Mm = (float*)(ws + 4096);                // aliases Wh (dead by then)
    float*          vo = (float*)d_out;

    k_pack       <<<320, 256, 0, stream>>>(wq, wk, wv, Wh, Wl, Wv);
    k_gemm_qk    <<<dim3(32, 16), 256, 0, stream>>>(Wh, Wl, x, bq, bk, QF, KF);
    k_scores_part<<<1024, 256, 0, stream>>>(QF, KF, Sp);
    k_softmax    <<<1, 64, 0, stream>>>(Sp, gamma, Mm);
    k_mix        <<<dim3(128, 8), 256, 0, stream>>>(Mm, x, Xm);
    k_gemm_v_res <<<dim3(32, 4, 16), 256, 0, stream>>>(Wv, Xm, bv, Mm, x, vo);
}